// Round 11
// baseline (274.680 us; speedup 1.0000x reference)
//
#include <hip/hip_runtime.h>
#include <hip/hip_bf16.h>

#define S_LEN 4096
#define Hn 8
#define DHn 64
#define Lc 128
#define HL 1024
#define KD 512   // inner dim of all GEMMs

typedef __attribute__((ext_vector_type(8))) short bshort8;
typedef __attribute__((ext_vector_type(4))) float f32x4;

__device__ __forceinline__ short f2bs(float f) {
    union { float f; unsigned u; } x; x.f = f;
    const unsigned r = x.u + 0x7FFFu + ((x.u >> 16) & 1u);
    return (short)(r >> 16);
}
__device__ __forceinline__ float bs2f(short s) {
    union { unsigned u; float f; } x; x.u = ((unsigned)(unsigned short)s) << 16;
    return x.f;
}

// async global(bf16 bits as short) -> LDS, 16B per lane (GEMMs only; LDS must be unpadded)
__device__ __forceinline__ void gl16(const short* g, short* l) {
    __builtin_amdgcn_global_load_lds((const __attribute__((address_space(1))) void*)g,
                                     (__attribute__((address_space(3))) void*)l, 16, 0, 0);
}

// ---------------- fused prep: X->bf16 + all weight transposes ----------------
__global__ __launch_bounds__(256) void prep_all(const float* __restrict__ X,
    const float* __restrict__ Wq, const float* __restrict__ Wk, const float* __restrict__ Wv,
    const float* __restrict__ Wd, const float* __restrict__ Wo,
    short* __restrict__ Xbf, short* __restrict__ WTall, short* __restrict__ WoT)
{
    const int t = threadIdx.x;
    int blk = blockIdx.x;
    if (blk < 2048) {
        const int i = (blk * 256 + t) * 8;
        const float4 a = *(const float4*)&X[i];
        const float4 b = *(const float4*)&X[i + 4];
        bshort8 o;
        o[0] = f2bs(a.x); o[1] = f2bs(a.y); o[2] = f2bs(a.z); o[3] = f2bs(a.w);
        o[4] = f2bs(b.x); o[5] = f2bs(b.y); o[6] = f2bs(b.z); o[7] = f2bs(b.w);
        *(bshort8*)&Xbf[i] = o;
        return;
    }
    blk -= 2048;
    const float* W; short* out; int N;
    if (blk < 256)       { W = Wq; out = WTall;              N = 512;  }
    else if (blk < 512)  { W = Wk; out = WTall + 512 * 512;  N = 512;  blk -= 256; }
    else if (blk < 768)  { W = Wv; out = WTall + 1024 * 512; N = 512;  blk -= 512; }
    else if (blk < 1280) { W = Wd; out = WTall + 1536 * 512; N = 1024; blk -= 768; }
    else                 { W = Wo; out = WoT;                N = 512;  blk -= 1280; }
    const int nb = N >> 5;
    const int n0 = (blk % nb) * 32, k0 = (blk / nb) * 32;
    __shared__ float Tl[32][33];
    const int tx = t & 31, ty = t >> 5;
#pragma unroll
    for (int i = ty; i < 32; i += 8)
        Tl[i][tx] = W[(size_t)(k0 + i) * N + n0 + tx];
    __syncthreads();
#pragma unroll
    for (int i = ty; i < 32; i += 8)
        out[(size_t)(n0 + i) * KD + k0 + tx] = f2bs(Tl[tx][i]);
}

// ---------------- fused projection GEMM (MFMA, BK=32, 128m x 256n, XCD-swizzled) ----------------
// 640 blocks: id%8 = XCD slice owning m-tiles [x*8,x*8+8) across all 10 n-tiles.
// Wave: 64m x 128n = 32 MFMAs per k-iter (2x the 128x128 tile) on the same
// conflict-free 32-short-row LDS layout. __launch_bounds__(256,2) caps VGPR for 2 blocks/CU.
__global__ __launch_bounds__(256, 2) void gemm_proj(const short* __restrict__ Xbf,
    const short* __restrict__ WT,
    const float* __restrict__ bq, const float* __restrict__ bk,
    const float* __restrict__ bv, const float* __restrict__ bd,
    short* __restrict__ Qbf, short* __restrict__ KbBf, short* __restrict__ VbBf,
    short* __restrict__ DlogBf)
{
    __shared__ __align__(16) short A_s[128 * 32];   // 8 KB
    __shared__ __align__(16) short B_s[256 * 32];   // 16 KB
    const int t = threadIdx.x;
    const int id = blockIdx.x;
    const int x8 = id & 7, j8 = id >> 3;            // 640 blocks total
    const int m0 = (x8 * 8 + (j8 & 7)) * 128;       // m-tile 0..63
    const int n0 = (j8 >> 3) * 256;                 // n-tile 0..9
    const int lane = t & 63, wave = t >> 6;
    const int wm = wave >> 1, wn = wave & 1;
    const int quad = lane >> 4, r15 = lane & 15;
    const int eOff = t * 8;
    const int am = eOff >> 5, ak = eOff & 31;
    f32x4 acc[4][8];
#pragma unroll
    for (int i = 0; i < 4; ++i)
#pragma unroll
        for (int j = 0; j < 8; ++j) acc[i][j] = (f32x4){0.f, 0.f, 0.f, 0.f};

    for (int kk = 0; kk < KD; kk += 32) {
        gl16(&Xbf[(size_t)(m0 + am) * KD + kk + ak],        &A_s[eOff]);
        gl16(&Xbf[(size_t)(m0 + 64 + am) * KD + kk + ak],   &A_s[2048 + eOff]);
#pragma unroll
        for (int r = 0; r < 4; ++r)
            gl16(&WT[(size_t)(n0 + r * 64 + am) * KD + kk + ak], &B_s[r * 2048 + eOff]);
        __syncthreads();
        bshort8 af[4];
#pragma unroll
        for (int i = 0; i < 4; ++i) af[i] = *(const bshort8*)&A_s[(wm * 64 + i * 16 + r15) * 32 + quad * 8];
#pragma unroll
        for (int j = 0; j < 8; ++j) {
            const bshort8 bfr = *(const bshort8*)&B_s[(wn * 128 + j * 16 + r15) * 32 + quad * 8];
#pragma unroll
            for (int i = 0; i < 4; ++i)
                acc[i][j] = __builtin_amdgcn_mfma_f32_16x16x32_bf16(af[i], bfr, acc[i][j], 0, 0, 0);
        }
        __syncthreads();
    }
    const int seg = (n0 >= 1536) ? 3 : (n0 >> 9);   // block-uniform (256-tiles don't cross 512 bounds)
#pragma unroll
    for (int i = 0; i < 4; ++i)
#pragma unroll
        for (int j = 0; j < 8; ++j)
#pragma unroll
            for (int r = 0; r < 4; ++r) {
                const int gm = m0 + wm * 64 + i * 16 + quad * 4 + r;
                const int gn = n0 + wn * 128 + j * 16 + r15;
                float v = acc[i][j][r];
                if (seg == 0) {
                    v = (v + bq[gn]) * 0.125f;
                    const int bb = gm >> 12, s = gm & 4095, hh = gn >> 6, d = gn & 63;
                    Qbf[((size_t)(bb * Hn + hh) * S_LEN + s) * DHn + d] = f2bs(v);
                } else if (seg == 1) {
                    KbBf[(size_t)gm * 512 + (gn - 512)] = f2bs(v + bk[gn - 512]);
                } else if (seg == 2) {
                    VbBf[(size_t)gm * 512 + (gn - 1024)] = f2bs(v + bv[gn - 1024]);
                } else {
                    DlogBf[(size_t)gm * 1024 + (gn - 1536)] = f2bs(v + bd[gn - 1536]);
                }
            }
}

// ---------------- output GEMM (MFMA): 64m x 128n tiles, 512 blocks, swizzled ----------------
__global__ __launch_bounds__(256) void gemm_out(const short* __restrict__ Abf,
    const short* __restrict__ WT, const float* __restrict__ bias, float* __restrict__ outp)
{
    __shared__ __align__(16) short A_s[64 * 32];    // 4 KB
    __shared__ __align__(16) short B_s[128 * 32];   // 8 KB
    const int t = threadIdx.x;
    const int id = blockIdx.x;
    const int x8 = id & 7, j8 = id >> 3;            // 512 blocks
    const int m0 = (x8 * 16 + (j8 & 15)) * 64;      // m-tile 0..127
    const int n0 = (j8 >> 4) * 128;                 // n-tile 0..3
    const int lane = t & 63, wave = t >> 6;
    const int quad = lane >> 4, r15 = lane & 15;
    const int eOff = t * 8;
    const int am = eOff >> 5, ak = eOff & 31;
    f32x4 acc[8];
#pragma unroll
    for (int j = 0; j < 8; ++j) acc[j] = (f32x4){0.f, 0.f, 0.f, 0.f};

    for (int kk = 0; kk < KD; kk += 32) {
        gl16(&Abf[(size_t)(m0 + am) * KD + kk + ak],      &A_s[eOff]);
        gl16(&WT[(size_t)(n0 + am) * KD + kk + ak],       &B_s[eOff]);
        gl16(&WT[(size_t)(n0 + 64 + am) * KD + kk + ak],  &B_s[2048 + eOff]);
        __syncthreads();
        const bshort8 af = *(const bshort8*)&A_s[(wave * 16 + r15) * 32 + quad * 8];
#pragma unroll
        for (int j = 0; j < 8; ++j) {
            const bshort8 bfr = *(const bshort8*)&B_s[(j * 16 + r15) * 32 + quad * 8];
            acc[j] = __builtin_amdgcn_mfma_f32_16x16x32_bf16(af, bfr, acc[j], 0, 0, 0);
        }
        __syncthreads();
    }
#pragma unroll
    for (int j = 0; j < 8; ++j)
#pragma unroll
        for (int r = 0; r < 4; ++r) {
            const int gm = m0 + wave * 16 + quad * 4 + r;
            const int gn = n0 + j * 16 + r15;
            outp[(size_t)gm * 512 + gn] = acc[j][r] + bias[gn];
        }
}

// ---------------- row LayerNorm over 512 (bf16 in, bf16 (B,H,S,DH) out) ----------------
__global__ __launch_bounds__(256) void ln_ip(const short* __restrict__ KbBf, const short* __restrict__ VbBf,
    const float* __restrict__ g, const float* __restrict__ beta,
    short* __restrict__ Kbf, short* __restrict__ Vbf)
{
    const short* src = blockIdx.y ? VbBf : KbBf;
    short* dst = blockIdx.y ? Vbf : Kbf;
    const int row = blockIdx.x, t = threadIdx.x;
    const size_t base = (size_t)row * 512;
    const float x0 = bs2f(src[base + t]);
    const float x1 = bs2f(src[base + t + 256]);
    float s = x0 + x1, ss = x0 * x0 + x1 * x1;
#pragma unroll
    for (int off = 32; off >= 1; off >>= 1) { s += __shfl_xor(s, off); ss += __shfl_xor(ss, off); }
    __shared__ float red[2][4];
    if ((t & 63) == 0) { red[0][t >> 6] = s; red[1][t >> 6] = ss; }
    __syncthreads();
    s = red[0][0] + red[0][1] + red[0][2] + red[0][3];
    ss = red[1][0] + red[1][1] + red[1][2] + red[1][3];
    const float mu = s * (1.f / 512.f);
    const float r = rsqrtf(ss * (1.f / 512.f) - mu * mu + 1e-5f);
    const int bb = row >> 12, sidx = row & 4095;
#pragma unroll
    for (int half = 0; half < 2; ++half) {
        const int c = t + half * 256;
        const float x = half ? x1 : x0;
        const float v = (x - mu) * r * g[c] + beta[c];
        dst[((size_t)(bb * Hn + (c >> 6)) * S_LEN + sidx) * DHn + (c & 63)] = f2bs(v);
    }
}

// ---------------- Kc/Vc stage 1 (MFMA): unnormalized exp partials + partZ ----------------
__global__ __launch_bounds__(256) void kcvc_mfma(const short* __restrict__ Dlog,
    const short* __restrict__ Kbf, const short* __restrict__ Vbf,
    short* __restrict__ partK, short* __restrict__ partV, float* __restrict__ partZ)
{
    __shared__ __align__(16) short aa[128 * 72];   // [l][s], 72-pad
    __shared__ __align__(16) short Kt[64 * 72];    // [d][s]
    __shared__ __align__(16) short Vt[64 * 72];
    __shared__ float zsh[256];
    const int t = threadIdx.x;
    const int seg = blockIdx.x, h = blockIdx.y, b = blockIdx.z;
    const int s0 = seg * 128;
    const size_t bh = (size_t)(b * Hn + h);
    const int lane = t & 63, wave = t >> 6;
    const int quad = lane >> 4, r15 = lane & 15;
    const int al = t & 127, ah = t >> 7;
    const int vj = t & 63, vd0 = (t >> 6) * 16;   // lane=j transpose: conflict-free writes
    float zacc = 0.f;
    f32x4 aK[2][4], aV[2][4];
#pragma unroll
    for (int i = 0; i < 2; ++i)
#pragma unroll
        for (int j = 0; j < 4; ++j) { aK[i][j] = (f32x4){0.f,0.f,0.f,0.f}; aV[i][j] = (f32x4){0.f,0.f,0.f,0.f}; }

    for (int c = 0; c < 2; ++c) {
        const int sc0 = s0 + c * 64;
        if (c) __syncthreads();
#pragma unroll
        for (int gch = 0; gch < 4; ++gch) {
            bshort8 o;
#pragma unroll
            for (int j = 0; j < 8; ++j) {
                const int s = sc0 + ah * 32 + gch * 8 + j;
                const float e = __expf(bs2f(Dlog[((size_t)b * S_LEN + s) * HL + h * Lc + al]));
                zacc += e;
                o[j] = f2bs(e);
            }
            *(bshort8*)&aa[al * 72 + ah * 32 + gch * 8] = o;
        }
        {
            const size_t rb = (bh * S_LEN + sc0 + vj) * DHn + vd0;
            const bshort8 k0 = *(const bshort8*)&Kbf[rb];
            const bshort8 k1 = *(const bshort8*)&Kbf[rb + 8];
            const bshort8 v0 = *(const bshort8*)&Vbf[rb];
            const bshort8 v1 = *(const bshort8*)&Vbf[rb + 8];
#pragma unroll
            for (int i = 0; i < 8; ++i) {
                Kt[(vd0 + i) * 72 + vj] = k0[i]; Kt[(vd0 + 8 + i) * 72 + vj] = k1[i];
                Vt[(vd0 + i) * 72 + vj] = v0[i]; Vt[(vd0 + 8 + i) * 72 + vj] = v1[i];
            }
        }
        __syncthreads();
#pragma unroll
        for (int ks = 0; ks < 2; ++ks) {
            const bshort8 a0 = *(const bshort8*)&aa[(wave * 32 + r15) * 72 + ks * 32 + quad * 8];
            const bshort8 a1 = *(const bshort8*)&aa[(wave * 32 + 16 + r15) * 72 + ks * 32 + quad * 8];
#pragma unroll
            for (int j = 0; j < 4; ++j) {
                const bshort8 bk = *(const bshort8*)&Kt[(j * 16 + r15) * 72 + ks * 32 + quad * 8];
                const bshort8 bv = *(const bshort8*)&Vt[(j * 16 + r15) * 72 + ks * 32 + quad * 8];
                aK[0][j] = __builtin_amdgcn_mfma_f32_16x16x32_bf16(a0, bk, aK[0][j], 0, 0, 0);
                aK[1][j] = __builtin_amdgcn_mfma_f32_16x16x32_bf16(a1, bk, aK[1][j], 0, 0, 0);
                aV[0][j] = __builtin_amdgcn_mfma_f32_16x16x32_bf16(a0, bv, aV[0][j], 0, 0, 0);
                aV[1][j] = __builtin_amdgcn_mfma_f32_16x16x32_bf16(a1, bv, aV[1][j], 0, 0, 0);
            }
        }
    }
    zsh[t] = zacc;
    __syncthreads();
    if (t < 128)
        partZ[((size_t)(bh * Lc + t)) * 32 + seg] = zsh[t] + zsh[t + 128];
#pragma unroll
    for (int i = 0; i < 2; ++i)
#pragma unroll
        for (int j = 0; j < 4; ++j)
#pragma unroll
            for (int r = 0; r < 4; ++r) {
                const int l = wave * 32 + i * 16 + quad * 4 + r;
                const int d = j * 16 + r15;
                const size_t o = (((size_t)(b * Lc + l)) * 32 + seg) * 512 + h * 64 + d;
                partK[o] = f2bs(aK[i][j][r]);
                partV[o] = f2bs(aV[i][j][r]);
            }
}

// ---------------- Kc/Vc stage 2: K and V handled by separate blocks (2x parallelism) ------
__global__ __launch_bounds__(256) void kcvc_s2(const short* __restrict__ partK,
    const short* __restrict__ partV, const float* __restrict__ partZ,
    const float* __restrict__ g, const float* __restrict__ beta,
    short* __restrict__ KcBf, short* __restrict__ VcBf)
{
    const int l = blockIdx.x, b = blockIdx.y, t = threadIdx.x;
    const short* part = blockIdx.z ? partV : partK;
    short* dst = blockIdx.z ? VcBf : KcBf;
    __shared__ float zh[8];
    if (t < 8) {
        float z = 0.f;
        const size_t zb = ((size_t)((b * Hn + t) * Lc + l)) * 32;
#pragma unroll
        for (int seg = 0; seg < 32; ++seg) z += partZ[zb + seg];
        zh[t] = 1.f / z;
    }
    const size_t base = ((size_t)(b * Lc + l)) * 32 * 512;
    float k0 = 0.f, k1 = 0.f;
    for (int ch = 0; ch < 32; ++ch) {
        const size_t o = base + (size_t)ch * 512;
        k0 += bs2f(part[o + t]);
        k1 += bs2f(part[o + t + 256]);
    }
    __syncthreads();
    const float z0 = zh[t >> 6], z1 = zh[(t + 256) >> 6];
    k0 *= z0; k1 *= z1;
    float sk = k0 + k1, ssk = k0 * k0 + k1 * k1;
#pragma unroll
    for (int off = 32; off >= 1; off >>= 1) {
        sk += __shfl_xor(sk, off); ssk += __shfl_xor(ssk, off);
    }
    __shared__ float red[2][4];
    if ((t & 63) == 0) { red[0][t >> 6] = sk; red[1][t >> 6] = ssk; }
    __syncthreads();
    sk = red[0][0] + red[0][1] + red[0][2] + red[0][3];
    ssk = red[1][0] + red[1][1] + red[1][2] + red[1][3];
    const float mu = sk * (1.f / 512.f);
    const float r = rsqrtf(ssk * (1.f / 512.f) - mu * mu + 1e-5f);
#pragma unroll
    for (int half = 0; half < 2; ++half) {
        const int c = t + half * 256;
        const float xk = half ? k1 : k0;
        const size_t o = ((size_t)(b * Hn + (c >> 6)) * Lc + l) * DHn + (c & 63);
        dst[o] = f2bs((xk - mu) * r * g[c] + beta[c]);
    }
}

// ---------------- MFMA flash attention: 128 q-rows per block (qt == window group) ----------------
__global__ __launch_bounds__(256) void attn_mfma(
    const short* __restrict__ Qbf, const short* __restrict__ Kbf, const short* __restrict__ Vbf,
    const short* __restrict__ KcBf, const short* __restrict__ VcBf,
    const int* __restrict__ mask, short* __restrict__ C)
{
    __shared__ __align__(16) short Q_l[128 * 72];   // [q][d]
    __shared__ __align__(16) short K_l[64 * 72];    // [j][d]
    __shared__ __align__(16) short Vt_l[64 * 72];   // [d][j]
    __shared__ __align__(16) short P_l[128 * 72];   // [q][j]
    __shared__ float vb[64];
    const int t = threadIdx.x;
    const int qt = blockIdx.x, h = blockIdx.y, b = blockIdx.z;
    const int q0 = qt * 128;
    const size_t bh = (size_t)(b * Hn + h);
    const int lane = t & 63, wave = t >> 6;
    const int quad = lane >> 4, r15 = lane & 15;
    const int sr = t >> 2, sc = (t & 3) * 16;      // 64-row padded staging
    const int vj = t & 63, vd0 = (t >> 6) * 16;    // lane=j V transpose

#pragma unroll
    for (int r = 0; r < 2; ++r) {
        const int row = r * 64 + sr;
        const size_t gq = (bh * S_LEN + q0 + row) * DHn + sc;
        const bshort8 a = *(const bshort8*)&Qbf[gq];
        const bshort8 b8 = *(const bshort8*)&Qbf[gq + 8];
        *(bshort8*)&Q_l[row * 72 + sc] = a;
        *(bshort8*)&Q_l[row * 72 + sc + 8] = b8;
    }
    f32x4 o[2][4];
#pragma unroll
    for (int i = 0; i < 2; ++i)
#pragma unroll
        for (int df = 0; df < 4; ++df) o[i][df] = (f32x4){0.f, 0.f, 0.f, 0.f};
    float lrow[2][4] = {{0.f, 0.f, 0.f, 0.f}, {0.f, 0.f, 0.f, 0.f}};

    for (int cc = 0; cc < 6; ++cc) {
        const short* ksrc; const short* vsrc;
        int sk0 = 0;
        if (cc < 2) {
            ksrc = &KcBf[(bh * Lc + cc * 64) * DHn];
            vsrc = &VcBf[(bh * Lc + cc * 64) * DHn];
        } else {
            sk0 = q0 - 64 + (cc - 2) * 64;
            if (sk0 < 0 || sk0 >= S_LEN) continue;   // 64-aligned: fully OOB -> skip (block-uniform)
            ksrc = &Kbf[(bh * S_LEN + sk0) * DHn];
            vsrc = &Vbf[(bh * S_LEN + sk0) * DHn];
        }
        __syncthreads();   // prev chunk's LDS reads done (also covers Q staging on first chunk)
        if (t < 64) {
            float v = 0.f;
            if (cc >= 2 && mask[b * S_LEN + sk0 + t] == 0) v = -1e30f;
            vb[t] = v;
        }
        {
            const bshort8 a = *(const bshort8*)&ksrc[sr * 64 + sc];
            const bshort8 b8 = *(const bshort8*)&ksrc[sr * 64 + sc + 8];
            *(bshort8*)&K_l[sr * 72 + sc] = a;
            *(bshort8*)&K_l[sr * 72 + sc + 8] = b8;
        }
        {
            const bshort8 v0 = *(const bshort8*)&vsrc[vj * 64 + vd0];
            const bshort8 v1 = *(const bshort8*)&vsrc[vj * 64 + vd0 + 8];
#pragma unroll
            for (int i = 0; i < 8; ++i) {
                Vt_l[(vd0 + i) * 72 + vj] = v0[i];
                Vt_l[(vd0 + 8 + i) * 72 + vj] = v1[i];
            }
        }
        __syncthreads();
        // QK^T: wave handles q rows [wave*32, wave*32+32) = 2 frags
        f32x4 c[2][4];
#pragma unroll
        for (int i = 0; i < 2; ++i)
#pragma unroll
            for (int jf = 0; jf < 4; ++jf) c[i][jf] = (f32x4){0.f, 0.f, 0.f, 0.f};
#pragma unroll
        for (int ks = 0; ks < 2; ++ks) {
            bshort8 aq[2];
#pragma unroll
            for (int i = 0; i < 2; ++i)
                aq[i] = *(const bshort8*)&Q_l[(wave * 32 + i * 16 + r15) * 72 + ks * 32 + quad * 8];
#pragma unroll
            for (int jf = 0; jf < 4; ++jf) {
                const bshort8 bk = *(const bshort8*)&K_l[(jf * 16 + r15) * 72 + ks * 32 + quad * 8];
                c[0][jf] = __builtin_amdgcn_mfma_f32_16x16x32_bf16(aq[0], bk, c[0][jf], 0, 0, 0);
                c[1][jf] = __builtin_amdgcn_mfma_f32_16x16x32_bf16(aq[1], bk, c[1][jf], 0, 0, 0);
            }
        }
        float vbl[4];
#pragma unroll
        for (int jf = 0; jf < 4; ++jf) vbl[jf] = vb[jf * 16 + r15];
        float sum[2][4] = {{0.f, 0.f, 0.f, 0.f}, {0.f, 0.f, 0.f, 0.f}};
#pragma unroll
        for (int i = 0; i < 2; ++i)
#pragma unroll
            for (int jf = 0; jf < 4; ++jf)
#pragma unroll
                for (int r = 0; r < 4; ++r) {
                    const float p = __expf(c[i][jf][r] + vbl[jf]);
                    sum[i][r] += p;
                    P_l[(wave * 32 + i * 16 + quad * 4 + r) * 72 + jf * 16 + r15] = f2bs(p);
                }
#pragma unroll
        for (int off = 1; off <= 8; off <<= 1)
#pragma unroll
            for (int i = 0; i < 2; ++i)
#pragma unroll
                for (int r = 0; r < 4; ++r) sum[i][r] += __shfl_xor(sum[i][r], off);
#pragma unroll
        for (int i = 0; i < 2; ++i)
#pragma unroll
            for (int r = 0; r < 4; ++r) lrow[i][r] += sum[i][r];
        // PV: A-frags from own wave's P rows (same-wave LDS); Vt synced above
#pragma unroll
        for (int ks = 0; ks < 2; ++ks) {
            bshort8 ap[2];
#pragma unroll
            for (int i = 0; i < 2; ++i)
                ap[i] = *(const bshort8*)&P_l[(wave * 32 + i * 16 + r15) * 72 + ks * 32 + quad * 8];
#pragma unroll
            for (int df = 0; df < 4; ++df) {
                const bshort8 bv = *(const bshort8*)&Vt_l[(df * 16 + r15) * 72 + ks * 32 + quad * 8];
                o[0][df] = __builtin_amdgcn_mfma_f32_16x16x32_bf16(ap[0], bv, o[0][df], 0, 0, 0);
                o[1][df] = __builtin_amdgcn_mfma_f32_16x16x32_bf16(ap[1], bv, o[1][df], 0, 0, 0);
            }
        }
    }
#pragma unroll
    for (int i = 0; i < 2; ++i)
#pragma unroll
        for (int r = 0; r < 4; ++r) {
            const int q = q0 + wave * 32 + i * 16 + quad * 4 + r;
            const float rl = (mask[b * S_LEN + q] == 0) ? 0.f : (1.f / lrow[i][r]);
            const size_t ob = ((size_t)b * S_LEN + q) * 512 + h * 64;
#pragma unroll
            for (int df = 0; df < 4; ++df)
                C[ob + df * 16 + r15] = f2bs(o[i][df][r] * rl);
        }
}

extern "C" void kernel_launch(void* const* d_in, const int* in_sizes, int n_in,
                              void* d_out, int out_size, void* d_ws, size_t ws_size,
                              hipStream_t stream) {
    (void)in_sizes; (void)n_in; (void)out_size; (void)ws_size;
    const float* X    = (const float*)d_in[0];
    const int*   mask = (const int*)d_in[1];
    const float* Wq = (const float*)d_in[2];  const float* bq = (const float*)d_in[3];
    const float* Wk = (const float*)d_in[4];  const float* bk = (const float*)d_in[5];
    const float* Wv = (const float*)d_in[6];  const float* bv = (const float*)d_in[7];
    const float* Wo = (const float*)d_in[8];  const float* bo = (const float*)d_in[9];
    const float* lnlg = (const float*)d_in[10]; const float* lnlb = (const float*)d_in[11];
    const float* lnsg = (const float*)d_in[12]; const float* lnsb = (const float*)d_in[13];
    const float* Wd = (const float*)d_in[14]; const float* bd = (const float*)d_in[15];

    short* sw = (short*)d_ws;
    short* Qbf    = sw;                        // 4,194,304 bf16 (B,H,S,DH), pre-scaled
    short* Kbf    = Qbf + 4194304;             // 4,194,304 bf16 (B,H,S,DH), LN'd
    short* Vbf    = Kbf + 4194304;             // 4,194,304 bf16 (B,H,S,DH), LN'd
    short* KbBf   = Vbf + 4194304;             // 4,194,304 bf16 row-major pre-LN K
    short* VbBf   = KbBf + 4194304;            // 4,194,304 bf16 row-major pre-LN V
    short* DlogBf = VbBf + 4194304;            // 8,388,608 bf16
    short* Xbf    = DlogBf + 8388608;          // 4,194,304 bf16 (reused: partK, then Cbf)
    short* WTall  = Xbf + 4194304;             // 1,310,720 bf16
    short* WoT    = WTall + 1310720;           // 262,144 bf16
    short* KcBf   = WoT + 262144;              // 131,072 bf16 (B,H,L,DH)
    short* VcBf   = KcBf + 131072;             // 131,072 bf16
    short* partV  = VcBf + 131072;             // 4,194,304 bf16
    float* partZ  = (float*)(partV + 4194304); // 65,536 f32 (b,h,l,seg)
    short* partK  = Xbf;                       // reuse (Xbf dead after gemm_proj)
    short* Cbf    = Xbf;                       // reuse (partK dead after kcvc_s2)
    // total ≈ 79.7 MB

    const dim3 blk(256);
    prep_all<<<3584, blk, 0, stream>>>(X, Wq, Wk, Wv, Wd, Wo, Xbf, WTall, WoT);
    gemm_proj<<<640, blk, 0, stream>>>(Xbf, WTall, bq, bk, bv, bd, Qbf, KbBf, VbBf, DlogBf);
    ln_ip<<<dim3(8192, 2), blk, 0, stream>>>(KbBf, VbBf, lnlg, lnlb, Kbf, Vbf);
    kcvc_mfma<<<dim3(32, 8, 2), blk, 0, stream>>>(DlogBf, Kbf, Vbf, partK, partV, partZ);
    kcvc_s2<<<dim3(128, 2, 2), blk, 0, stream>>>(partK, partV, partZ, lnsg, lnsb, KcBf, VcBf);
    attn_mfma<<<dim3(32, 8, 2), blk, 0, stream>>>(Qbf, Kbf, Vbf, KcBf, VcBf, mask, Cbf);
    gemm_out<<<512, blk, 0, stream>>>(Cbf, WoT, bo, (float*)d_out);
}